// Round 1
// baseline (543.023 us; speedup 1.0000x reference)
//
#include <hip/hip_runtime.h>
#include <hip/hip_bf16.h>
#include <math.h>

// Fused LabelSmoothingCrossEntropy + Focal + SuperLoss(LambertW) over
// [B=2048, C=50257] fp32 logits. Memory-bound: one pass over 412 MB.
//
// Kernel 1: one block per row. Online-softmax (running max + rescaled sum)
//   fused with sum(x) in a single sweep; float4 body with alignment peel
//   (rows start at element row*C, C % 4 == 1, so alignment rotates per row).
//   Thread 0 finishes the per-row scalar chain (ce -> focal -> LambertW ->
//   sl) in double and writes {sl, rowloss} to workspace.
// Kernel 2: single block reduces 2048 rows, emits the two scalars.

#define EPS_LS 0.01
#define LAM 0.5
#define ALPHA 0.25

__global__ __launch_bounds__(256) void
row_kernel(const float* __restrict__ x, const int* __restrict__ tgt,
           double* __restrict__ ws, int B, int C) {
    const int row = blockIdx.x;
    const int tid = threadIdx.x;
    const float* xr = x + (size_t)row * (size_t)C;

    float m  = -3.402823466e38f;   // running max
    float s  = 0.0f;               // running sum exp(x - m)
    float sx = 0.0f;               // running sum x

    // peel to 16B alignment
    const int mis = (int)(((size_t)row * (size_t)C) & 3);
    const int pre = (4 - mis) & 3;
    if (tid < pre) {
        float v = xr[tid];
        m = v; s = 1.0f; sx = v;
    }
    const int nvec = (C - pre) >> 2;
    const float4* xv = reinterpret_cast<const float4*>(xr + pre);
    for (int i = tid; i < nvec; i += 256) {
        float4 v = xv[i];
        float mx = fmaxf(fmaxf(v.x, v.y), fmaxf(v.z, v.w));
        float nm = fmaxf(m, mx);
        s = s * __expf(m - nm)
          + __expf(v.x - nm) + __expf(v.y - nm)
          + __expf(v.z - nm) + __expf(v.w - nm);
        m = nm;
        sx += (v.x + v.y) + (v.z + v.w);
    }
    const int done = pre + (nvec << 2);
    const int rem = C - done;      // 0..3 tail elements
    if (tid < rem) {
        float v = xr[done + tid];
        float nm = fmaxf(m, v);
        s = s * __expf(m - nm) + __expf(v - nm);
        m = nm;
        sx += v;
    }

    // wave(64) butterfly-free down-reduce of (m, s) pair + sx
    for (int off = 32; off > 0; off >>= 1) {
        float mo  = __shfl_down(m, off, 64);
        float so  = __shfl_down(s, off, 64);
        float sxo = __shfl_down(sx, off, 64);
        float nm = fmaxf(m, mo);
        s = s * __expf(m - nm) + so * __expf(mo - nm);
        m = nm;
        sx += sxo;
    }

    __shared__ float sh_m[4], sh_s[4], sh_sx[4];
    const int wave = tid >> 6, lane = tid & 63;
    if (lane == 0) { sh_m[wave] = m; sh_s[wave] = s; sh_sx[wave] = sx; }
    __syncthreads();

    if (tid == 0) {
        float M = sh_m[0], S = sh_s[0], SX = sh_sx[0];
        for (int wv = 1; wv < 4; ++wv) {
            float nm = fmaxf(M, sh_m[wv]);
            S = S * __expf(M - nm) + sh_s[wv] * __expf(sh_m[wv] - nm);
            M = nm;
            SX += sh_sx[wv];
        }
        // scalar tail in double (2048 of these total -- negligible cost)
        const double lse = log((double)S);
        const double xt  = (double)xr[tgt[row]];
        const double ce  = (double)M + lse - xt;          // -log_softmax[target]
        const double pt  = exp(-ce);
        const double omp = 1.0 - pt;
        const double focal = ALPHA * omp * omp * ce;
        const double tau = log((double)C);
        const double cl  = focal - tau;
        // SuperLoss sigma via principal-branch Lambert W (Halley, 20 iters)
        const double Econst = 2.718281828459045235360287;
        double y_ = 0.5 * fmax(-2.0 / Econst, cl / LAM);
        double y  = fmax(y_, -exp(-1.0) + 1e-7);
        double p  = sqrt(2.0 * (Econst * y + 1.0));
        double w  = (y < 0.0) ? (-1.0 + p - p * p / 3.0) : log1p(y);
        for (int it = 0; it < 20; ++it) {
            double ew = exp(w);
            double f  = w * ew - y;
            double w1 = w + 1.0;
            w = w - f / (ew * w1 - (w + 2.0) * f / (2.0 * w1));
        }
        const double sigma = exp(-w);
        const double lw = log(sigma);
        const double sl = cl * sigma + LAM * lw * lw;
        // -sum(log_softmax) over the row = C*(max+lse) - sum(x)
        const double rowloss = (double)C * ((double)M + lse) - (double)SX;
        ws[row]     = sl;
        ws[B + row] = rowloss;
    }
}

__global__ __launch_bounds__(256) void
finalize_kernel(const double* __restrict__ ws, float* __restrict__ out,
                int B, int C) {
    __shared__ double shA[256], shB[256];
    const int tid = threadIdx.x;
    double a = 0.0, b = 0.0;
    for (int i = tid; i < B; i += 256) {
        a += ws[i];
        b += ws[B + i];
    }
    shA[tid] = a; shB[tid] = b;
    __syncthreads();
    for (int off = 128; off > 0; off >>= 1) {
        if (tid < off) { shA[tid] += shA[tid + off]; shB[tid] += shB[tid + off]; }
        __syncthreads();
    }
    if (tid == 0) {
        const double sl_mean = shA[0] / (double)B;
        const double loss    = shB[0] / (double)B;
        const double loss_cls = loss * (EPS_LS / (double)C) + (1.0 - EPS_LS) * sl_mean;
        out[0] = (float)loss_cls;
        out[1] = (float)exp(sl_mean);
    }
}

extern "C" void kernel_launch(void* const* d_in, const int* in_sizes, int n_in,
                              void* d_out, int out_size, void* d_ws, size_t ws_size,
                              hipStream_t stream) {
    const float* x   = (const float*)d_in[0];
    const int*   tgt = (const int*)d_in[1];
    float* out = (float*)d_out;
    double* ws = (double*)d_ws;

    const int B = in_sizes[1];
    const int C = in_sizes[0] / B;

    row_kernel<<<B, 256, 0, stream>>>(x, tgt, ws, B, C);
    finalize_kernel<<<1, 256, 0, stream>>>(ws, out, B, C);
}

// Round 3
// 534.990 us; speedup vs baseline: 1.0150x; 1.0150x over previous
//
#include <hip/hip_runtime.h>
#include <hip/hip_bf16.h>
#include <math.h>

// Fused LabelSmoothingCrossEntropy + Focal + SuperLoss(LambertW) over
// [B=2048, C=50257] fp32 logits. Memory-bound: one pass over 412 MB.
//
// R2: fix nontemporal-load pointer type (clang ext_vector_type, not
// HIP_vector_type). Structure unchanged from R1:
//  - row_kernel fp32-only, online softmax + sum(x), 2x independent
//    accumulators, nontemporal 16B loads, {M,S,SX} -> ws per row.
//  - finalize_kernel (1 block) does the f64 focal/LambertW chain + reduce.

#define EPS_LS 0.01
#define LAM 0.5
#define ALPHA 0.25

typedef float vf4 __attribute__((ext_vector_type(4)));

struct Acc { float m, s, sx; };

__device__ __forceinline__ void acc_vec(Acc& a, vf4 v) {
    float mx = fmaxf(fmaxf(v.x, v.y), fmaxf(v.z, v.w));
    float nm = fmaxf(a.m, mx);
    a.s = a.s * __expf(a.m - nm)
        + __expf(v.x - nm) + __expf(v.y - nm)
        + __expf(v.z - nm) + __expf(v.w - nm);
    a.m = nm;
    a.sx += (v.x + v.y) + (v.z + v.w);
}

__device__ __forceinline__ void acc_merge(Acc& a, float mo, float so, float sxo) {
    float nm = fmaxf(a.m, mo);
    a.s = a.s * __expf(a.m - nm) + so * __expf(mo - nm);
    a.m = nm;
    a.sx += sxo;
}

__global__ __launch_bounds__(256) void
row_kernel(const float* __restrict__ x, float4* __restrict__ ws, int C) {
    const int row = blockIdx.x;
    const int tid = threadIdx.x;
    const float* xr = x + (size_t)row * (size_t)C;

    Acc a0 = { -3.402823466e38f, 0.0f, 0.0f };
    Acc a1 = { -3.402823466e38f, 0.0f, 0.0f };

    // peel to 16B alignment (rows start at row*C, C%4==1 -> rotates)
    const int mis = (int)(((size_t)row * (size_t)C) & 3);
    const int pre = (4 - mis) & 3;
    if (tid < pre) {
        float v = xr[tid];
        a0.m = v; a0.s = 1.0f; a0.sx = v;
    }
    const int nvec = (C - pre) >> 2;
    const vf4* xv = reinterpret_cast<const vf4*>(xr + pre);

    int i = tid;
    for (; i + 256 < nvec; i += 512) {
        vf4 v0 = __builtin_nontemporal_load(&xv[i]);
        vf4 v1 = __builtin_nontemporal_load(&xv[i + 256]);
        acc_vec(a0, v0);
        acc_vec(a1, v1);
    }
    if (i < nvec) {
        vf4 v0 = __builtin_nontemporal_load(&xv[i]);
        acc_vec(a0, v0);
    }
    // scalar tail (0..3 elements)
    const int done = pre + (nvec << 2);
    const int rem = C - done;
    if (tid < rem) {
        float v = xr[done + tid];
        float nm = fmaxf(a0.m, v);
        a0.s = a0.s * __expf(a0.m - nm) + __expf(v - nm);
        a0.m = nm;
        a0.sx += v;
    }
    acc_merge(a0, a1.m, a1.s, a1.sx);

    // wave(64) reduce of (m, s, sx)
    for (int off = 32; off > 0; off >>= 1) {
        float mo  = __shfl_down(a0.m,  off, 64);
        float so  = __shfl_down(a0.s,  off, 64);
        float sxo = __shfl_down(a0.sx, off, 64);
        acc_merge(a0, mo, so, sxo);
    }

    __shared__ float sh_m[4], sh_s[4], sh_sx[4];
    const int wave = tid >> 6, lane = tid & 63;
    if (lane == 0) { sh_m[wave] = a0.m; sh_s[wave] = a0.s; sh_sx[wave] = a0.sx; }
    __syncthreads();

    if (tid == 0) {
        Acc A = { sh_m[0], sh_s[0], sh_sx[0] };
        for (int wv = 1; wv < 4; ++wv) acc_merge(A, sh_m[wv], sh_s[wv], sh_sx[wv]);
        ws[row] = make_float4(A.m, A.s, A.sx, 0.0f);
    }
}

__global__ __launch_bounds__(256) void
finalize_kernel(const float4* __restrict__ ws, const float* __restrict__ x,
                const int* __restrict__ tgt, float* __restrict__ out,
                int B, int C) {
    __shared__ double shA[256], shB[256];
    const int tid = threadIdx.x;
    const double tau = log((double)C);
    const double Econst = 2.718281828459045235360287;

    double sl_sum = 0.0, loss_sum = 0.0;
    for (int row = tid; row < B; row += 256) {
        float4 r = ws[row];
        const double M = (double)r.x;
        const double lse = log((double)r.y);
        const double SX = (double)r.z;
        const double xt = (double)x[(size_t)row * (size_t)C + tgt[row]];
        const double ce = M + lse - xt;             // -log_softmax[target]
        const double pt = exp(-ce);
        const double omp = 1.0 - pt;
        const double focal = ALPHA * omp * omp * ce;
        const double cl = focal - tau;
        // SuperLoss sigma via principal-branch Lambert W (Halley, 20 iters)
        double y_ = 0.5 * fmax(-2.0 / Econst, cl / LAM);
        double y  = fmax(y_, -exp(-1.0) + 1e-7);
        double p  = sqrt(2.0 * (Econst * y + 1.0));
        double w  = (y < 0.0) ? (-1.0 + p - p * p / 3.0) : log1p(y);
        for (int it = 0; it < 20; ++it) {
            double ew = exp(w);
            double f  = w * ew - y;
            double w1 = w + 1.0;
            w = w - f / (ew * w1 - (w + 2.0) * f / (2.0 * w1));
        }
        const double sigma = exp(-w);
        const double lw = log(sigma);
        sl_sum   += cl * sigma + LAM * lw * lw;
        loss_sum += (double)C * (M + lse) - SX;     // -sum(log_softmax) of row
    }
    shA[tid] = sl_sum; shB[tid] = loss_sum;
    __syncthreads();
    for (int off = 128; off > 0; off >>= 1) {
        if (tid < off) { shA[tid] += shA[tid + off]; shB[tid] += shB[tid + off]; }
        __syncthreads();
    }
    if (tid == 0) {
        const double sl_mean = shA[0] / (double)B;
        const double loss    = shB[0] / (double)B;
        const double loss_cls = loss * (EPS_LS / (double)C) + (1.0 - EPS_LS) * sl_mean;
        out[0] = (float)loss_cls;
        out[1] = (float)exp(sl_mean);
    }
}

extern "C" void kernel_launch(void* const* d_in, const int* in_sizes, int n_in,
                              void* d_out, int out_size, void* d_ws, size_t ws_size,
                              hipStream_t stream) {
    const float* x   = (const float*)d_in[0];
    const int*   tgt = (const int*)d_in[1];
    float* out = (float*)d_out;
    float4* ws = (float4*)d_ws;

    const int B = in_sizes[1];
    const int C = in_sizes[0] / B;

    row_kernel<<<B, 256, 0, stream>>>(x, ws, C);
    finalize_kernel<<<1, 256, 0, stream>>>(ws, x, tgt, out, B, C);
}